// Round 11
// baseline (131.680 us; speedup 1.0000x reference)
//
#include <hip/hip_runtime.h>

#define T_DIM 2000
#define N_DIM 128
#define IN_DIM 256
#define OUT_C 46
#define NROWS (T_DIM * N_DIM)
#define NCHUNK 250
#define CLEN 8
#define NSUPER 25
#define SLEN 10

typedef short bf16x8 __attribute__((ext_vector_type(8)));
typedef float f32x4 __attribute__((ext_vector_type(4)));

union F8U { bf16x8 v; uint32_t u[4]; };

__device__ __forceinline__ uint32_t cvtpk(float lo, float hi) {
  uint32_t r;
  asm("v_cvt_pk_bf16_f32 %0, %1, %2" : "=v"(r) : "v"(lo), "v"(hi));
  return r;
}

__device__ __forceinline__ float bf2f(unsigned short u) {
  uint32_t w = (uint32_t)u << 16;
  return __builtin_bit_cast(float, w);
}

#define LDSK 264   // padded W row length (shorts)
#define YROW 132   // padded Yl row length (shorts); 264B keeps 8B alignment

// ---------------------------------------------------------------------------
// k1_fused: block = 1024 threads = one chunk (8 t x 128 n).
//  Phase 1 (16 waves): y = x@W^T + b via MFMA (W in LDS bf16, half-tile
//    ping-pong A prefetch).  Trans scores -> LDS Yl AND global wsYT (bf16,
//    transposed [t][c][n]); mods -> global wsMod.
//  Phase 2 (threads 0..127, after one barrier): build this chunk's 8x8
//    linear-space transition-matrix product directly from Yl (no global
//    re-read), column-wise M update to stay under the 128-VGPR cap.
// ---------------------------------------------------------------------------
__global__ __launch_bounds__(1024, 4) void k1_fused(const float* __restrict__ x,
                                                    const float* __restrict__ W,
                                                    const float* __restrict__ b,
                                                    unsigned short* __restrict__ wsYT,
                                                    float* __restrict__ wsMod,
                                                    float* __restrict__ wsM,
                                                    float* __restrict__ wsScale) {
  __shared__ unsigned short Wl[43 * LDSK];   // 22.7 KB
  __shared__ unsigned short Yl[8 * 40 * YROW]; // 84.5 KB
  const int tid  = threadIdx.x;
  const int lane = tid & 63;
  const int wv   = tid >> 6;     // 0..15
  const int ln   = lane & 15;
  const int lh   = lane >> 4;

  {  // stage W as bf16 into padded LDS rows (43*128 = 5504 dword-pairs)
    uint32_t* Wd = reinterpret_cast<uint32_t*>(Wl);
#pragma unroll
    for (int it = 0; it < 6; ++it) {
      int e = tid + it * 1024;
      if (e < 43 * 128) {
        int n = e >> 7, kp = e & 127;
        float2 w = *reinterpret_cast<const float2*>(W + (size_t)n * IN_DIM + 2 * kp);
        Wd[n * (LDSK / 2) + kp] = cvtpk(w.x, w.y);
      }
    }
  }
  float bias[3];
#pragma unroll
  for (int nt = 0; nt < 3; ++nt) {
    int n = nt * 16 + ln;
    bias[nt] = b[n > 42 ? 42 : n];
  }
  __syncthreads();

  // ---- Phase 1: GEMM.  wave wv handles t = wv>>1, n-half = (wv&1)*64 ----
  const int tloc  = wv >> 1;
  const int nhalf = (wv & 1) * 64;
  const int tg    = blockIdx.x * 8 + tloc;
  const float* xbase = x + ((size_t)tg * 128 + nhalf + ln) * IN_DIM + lh * 8;

  f32x4 bufA[8], bufB[8];
  f32x4 zero = {0.f, 0.f, 0.f, 0.f};
  f32x4 acc[3] = {zero, zero, zero};

#define LOADH(BUF, T, HF) do {                                               \
    const float* _p = xbase + (size_t)(T) * (16 * IN_DIM) + (HF) * 128;      \
    _Pragma("unroll")                                                        \
    for (int _s = 0; _s < 4; ++_s) {                                         \
      BUF[_s]     = *reinterpret_cast<const f32x4*>(_p + _s * 32);           \
      BUF[_s + 4] = *reinterpret_cast<const f32x4*>(_p + _s * 32 + 4);       \
    }                                                                        \
  } while (0)

#define COMPH(BUF, HF) do {                                                  \
    _Pragma("unroll")                                                        \
    for (int _s2 = 0; _s2 < 4; ++_s2) {                                      \
      F8U _af;                                                               \
      _af.u[0] = cvtpk(BUF[_s2].x, BUF[_s2].y);                              \
      _af.u[1] = cvtpk(BUF[_s2].z, BUF[_s2].w);                              \
      _af.u[2] = cvtpk(BUF[_s2 + 4].x, BUF[_s2 + 4].y);                      \
      _af.u[3] = cvtpk(BUF[_s2 + 4].z, BUF[_s2 + 4].w);                      \
      const int _s = (HF) * 4 + _s2;                                         \
      _Pragma("unroll")                                                      \
      for (int _nt = 0; _nt < 3; ++_nt) {                                    \
        const bf16x8 _bf = *reinterpret_cast<const bf16x8*>(                 \
            &Wl[(_nt * 16 + ln) * LDSK + _s * 32 + lh * 8]);                 \
        acc[_nt] = __builtin_amdgcn_mfma_f32_16x16x32_bf16(_af.v, _bf,       \
                                                           acc[_nt], 0, 0, 0);\
      }                                                                      \
    }                                                                        \
  } while (0)

  LOADH(bufA, 0, 0);
  LOADH(bufB, 0, 1);
#pragma unroll 1
  for (int t = 0; t < 4; ++t) {
    COMPH(bufA, 0);
    if (t < 3) LOADH(bufA, t + 1, 0);
    COMPH(bufB, 1);
    if (t < 3) LOADH(bufB, t + 1, 1);
    const int n0 = nhalf + t * 16 + lh * 4;   // 4 consecutive n
#pragma unroll
    for (int nt = 0; nt < 3; ++nt) {
      const int c = nt * 16 + ln;
      if (nt < 2 || ln < 8) {        // trans scores c<40
        uint32_t d0 = cvtpk(acc[nt][0] + bias[nt], acc[nt][1] + bias[nt]);
        uint32_t d1 = cvtpk(acc[nt][2] + bias[nt], acc[nt][3] + bias[nt]);
        uint2 v; v.x = d0; v.y = d1;
        *reinterpret_cast<uint2*>(wsYT + ((size_t)tg * 40 + c) * 128 + n0) = v;
        *reinterpret_cast<uint2*>(&Yl[(tloc * 40 + c) * YROW + n0]) = v;
      } else if (ln < 11) {          // c = 40..42 -> fp32 wsMod[t][c-40][n]
        float4 v;
        v.x = acc[2][0] + bias[2]; v.y = acc[2][1] + bias[2];
        v.z = acc[2][2] + bias[2]; v.w = acc[2][3] + bias[2];
        *reinterpret_cast<float4*>(
            wsMod + ((size_t)tg * 3 + (ln - 8)) * 128 + n0) = v;
      }
      acc[nt] = zero;
    }
  }
#undef LOADH
#undef COMPH

  __syncthreads();

  // ---- Phase 2: chunk scan from LDS (threads 0..127, one lane per n) ----
  if (tid < 128) {
    const int n = tid;
    float M[8][8];
    float lsc = 0.f;

#define YL(T, Q) bf2f(Yl[((T) * 40 + (Q)) * YROW + n])

    {  // INITM from t-row 0 (each exp used once -> no e array)
#pragma unroll
      for (int i = 0; i < 4; ++i)
#pragma unroll
        for (int j = 0; j < 8; ++j) M[i][j] = __expf(YL(0, 8 * i + j));
#pragma unroll
      for (int d = 0; d < 4; ++d) {
#pragma unroll
        for (int j = 0; j < 8; ++j) M[4 + d][j] = 0.f;
        M[4 + d][d]     = __expf(YL(0, 32 + d));
        M[4 + d][4 + d] = __expf(YL(0, 36 + d));
      }
    }

#define STEPM(T) do {                                                        \
    float e[40];                                                             \
    _Pragma("unroll")                                                        \
    for (int _q = 0; _q < 40; ++_q) e[_q] = __expf(YL(T, _q));               \
    _Pragma("unroll")                                                        \
    for (int _j = 0; _j < 8; ++_j) {  /* column-wise: col j independent */   \
      float c0 = M[0][_j], c1 = M[1][_j], c2 = M[2][_j], c3 = M[3][_j];      \
      float c4 = M[4][_j], c5 = M[5][_j], c6 = M[6][_j], c7 = M[7][_j];      \
      _Pragma("unroll")                                                      \
      for (int _i = 0; _i < 4; ++_i) {                                       \
        float _a = e[8*_i+0]*c0 + e[8*_i+1]*c1;                              \
        float _b2 = e[8*_i+2]*c2 + e[8*_i+3]*c3;                             \
        float _c = e[8*_i+4]*c4 + e[8*_i+5]*c5;                              \
        float _d = e[8*_i+6]*c6 + e[8*_i+7]*c7;                              \
        M[_i][_j] = (_a + _b2) + (_c + _d);                                  \
      }                                                                      \
      M[4][_j] = e[32]*c0 + e[36]*c4;                                        \
      M[5][_j] = e[33]*c1 + e[37]*c5;                                        \
      M[6][_j] = e[34]*c2 + e[38]*c6;                                        \
      M[7][_j] = e[35]*c3 + e[39]*c7;                                        \
    }                                                                        \
  } while (0)

#define RENORM do {                                                          \
    float _S = 0.f;                                                          \
    _Pragma("unroll")                                                        \
    for (int _i = 0; _i < 8; ++_i)                                           \
      _Pragma("unroll")                                                      \
      for (int _j = 0; _j < 8; ++_j) _S += M[_i][_j];                        \
    lsc += __logf(_S);                                                       \
    const float _inv = 1.0f / _S;                                            \
    _Pragma("unroll")                                                        \
    for (int _i = 0; _i < 8; ++_i)                                           \
      _Pragma("unroll")                                                      \
      for (int _j = 0; _j < 8; ++_j) M[_i][_j] *= _inv;                      \
  } while (0)

    STEPM(1);
    STEPM(2);
    STEPM(3);
    RENORM;
    STEPM(4);
    STEPM(5);
    STEPM(6);
    STEPM(7);
    RENORM;
#undef STEPM
#undef RENORM
#undef YL

    float* dst = wsM + (size_t)(blockIdx.x * N_DIM + n) * 64;
#pragma unroll
    for (int q = 0; q < 16; ++q) {
      float4 v;
      v.x = M[q >> 1][(q & 1) * 4 + 0];
      v.y = M[q >> 1][(q & 1) * 4 + 1];
      v.z = M[q >> 1][(q & 1) * 4 + 2];
      v.w = M[q >> 1][(q & 1) * 4 + 3];
      reinterpret_cast<float4*>(dst)[q] = v;
    }
    wsScale[blockIdx.x * N_DIM + n] = lsc;
  }
}

// ---------------------------------------------------------------------------
// k2c: fold SLEN=10 chunk matrices into one super-matrix, ping-pong prefetch.
// ---------------------------------------------------------------------------
__global__ __launch_bounds__(128, 1) void k2c_super(const float* __restrict__ wsM,
                                                    const float* __restrict__ wsScale,
                                                    float* __restrict__ wsM2,
                                                    float* __restrict__ wsScale2) {
  const int sI = blockIdx.x;     // 0..24
  const int n  = threadIdx.x;    // 0..127
  const int c0 = sI * SLEN;

  float A[8][8], B0[8][8], B1[8][8];
  float lsc = 0.f;
#pragma unroll
  for (int u = 0; u < SLEN; ++u) lsc += wsScale[(c0 + u) * N_DIM + n];

#define LOADM(DST, CIDX) do {                                                \
    const float4* _p = reinterpret_cast<const float4*>(                      \
        wsM + (size_t)((CIDX) * N_DIM + n) * 64);                            \
    _Pragma("unroll")                                                        \
    for (int _q = 0; _q < 16; ++_q) {                                        \
      float4 _v = _p[_q];                                                    \
      DST[_q >> 1][(_q & 1) * 4 + 0] = _v.x;                                 \
      DST[_q >> 1][(_q & 1) * 4 + 1] = _v.y;                                 \
      DST[_q >> 1][(_q & 1) * 4 + 2] = _v.z;                                 \
      DST[_q >> 1][(_q & 1) * 4 + 3] = _v.w;                                 \
    }                                                                        \
  } while (0)

#define FOLD(BB) do {                                                        \
    float C[8][8];                                                           \
    _Pragma("unroll")                                                        \
    for (int _i = 0; _i < 8; ++_i)                                           \
      _Pragma("unroll")                                                      \
      for (int _j = 0; _j < 8; ++_j) {                                       \
        float _a = BB[_i][0]*A[0][_j] + BB[_i][1]*A[1][_j];                  \
        float _b = BB[_i][2]*A[2][_j] + BB[_i][3]*A[3][_j];                  \
        float _c = BB[_i][4]*A[4][_j] + BB[_i][5]*A[5][_j];                  \
        float _d = BB[_i][6]*A[6][_j] + BB[_i][7]*A[7][_j];                  \
        C[_i][_j] = (_a + _b) + (_c + _d);                                   \
      }                                                                      \
    float _S = 0.f;                                                          \
    _Pragma("unroll")                                                        \
    for (int _i = 0; _i < 8; ++_i)                                           \
      _Pragma("unroll")                                                      \
      for (int _j = 0; _j < 8; ++_j) _S += C[_i][_j];                        \
    lsc += __logf(_S);                                                       \
    const float _inv = 1.0f / _S;                                            \
    _Pragma("unroll")                                                        \
    for (int _i = 0; _i < 8; ++_i)                                           \
      _Pragma("unroll")                                                      \
      for (int _j = 0; _j < 8; ++_j) A[_i][_j] = C[_i][_j] * _inv;           \
  } while (0)

  LOADM(A, c0);
  LOADM(B0, c0 + 1);
  LOADM(B1, c0 + 2);
  FOLD(B0); LOADM(B0, c0 + 3);
  FOLD(B1); LOADM(B1, c0 + 4);
  FOLD(B0); LOADM(B0, c0 + 5);
  FOLD(B1); LOADM(B1, c0 + 6);
  FOLD(B0); LOADM(B0, c0 + 7);
  FOLD(B1); LOADM(B1, c0 + 8);
  FOLD(B0); LOADM(B0, c0 + 9);
  FOLD(B1);
  FOLD(B0);
#undef LOADM
#undef FOLD

  float* dst = wsM2 + (size_t)(sI * N_DIM + n) * 64;
#pragma unroll
  for (int q = 0; q < 16; ++q) {
    float4 v;
    v.x = A[q >> 1][(q & 1) * 4 + 0];
    v.y = A[q >> 1][(q & 1) * 4 + 1];
    v.z = A[q >> 1][(q & 1) * 4 + 2];
    v.w = A[q >> 1][(q & 1) * 4 + 3];
    reinterpret_cast<float4*>(dst)[q] = v;
  }
  wsScale2[sI * N_DIM + n] = lsc;
}

// ---------------------------------------------------------------------------
// k2b: fold p0 through the 25 super-matrices. 8 lanes per column n.
// ---------------------------------------------------------------------------
__global__ __launch_bounds__(128, 1) void k2b_fold(const float* __restrict__ wsM2,
                                                   const float* __restrict__ wsScale2,
                                                   float* __restrict__ wsLZ) {
  const int tid = threadIdx.x;
  const int n = blockIdx.x * 16 + (tid >> 3);
  const int i = tid & 7;
  const int gbase = (tid & 63) & ~7;

  float4 r0[NSUPER], r1[NSUPER];
  float sc[NSUPER];
#pragma unroll
  for (int s = 0; s < NSUPER; ++s) {
    const float* Mp = wsM2 + ((size_t)(s * N_DIM + n) * 64 + i * 8);
    r0[s] = *reinterpret_cast<const float4*>(Mp);
    r1[s] = *reinterpret_cast<const float4*>(Mp + 4);
    sc[s] = wsScale2[s * N_DIM + n];
  }

  float p[8] = {1.f, 1.f, 1.f, 1.f, 0.f, 0.f, 0.f, 0.f};
  float lz = 0.f;
#pragma unroll
  for (int s = 0; s < NSUPER; ++s) {
    float np = r0[s].x * p[0] + r0[s].y * p[1] + r0[s].z * p[2] + r0[s].w * p[3]
             + r1[s].x * p[4] + r1[s].y * p[5] + r1[s].z * p[6] + r1[s].w * p[7];
#pragma unroll
    for (int j = 0; j < 8; ++j) p[j] = __shfl(np, gbase + j, 64);
    float S = ((p[0] + p[1]) + (p[2] + p[3])) + ((p[4] + p[5]) + (p[6] + p[7]));
    lz += __logf(S) + sc[s];
    const float inv = 1.0f / S;
#pragma unroll
    for (int j = 0; j < 8; ++j) p[j] *= inv;
  }
  if (i == 0) wsLZ[n] = lz * (1.0f / (float)T_DIM);
}

// ---------------------------------------------------------------------------
// k3: write the WHOLE output.  128 threads, 2 t x 128 n = 256 rows/block;
// each thread builds TWO adjacent-n rows.  Rows staged in padded LDS, then
// flat coalesced copy with NONTEMPORAL stores (out is write-once; don't
// evict the wsYT/wsMod this kernel still reads).
// ---------------------------------------------------------------------------
__global__ __launch_bounds__(128, 3) void k3_out(const unsigned short* __restrict__ wsYT,
                                                 const float* __restrict__ wsMod,
                                                 const float* __restrict__ wsLZ,
                                                 float* __restrict__ out) {
  __shared__ float L[256 * 47];
  const int tid = threadIdx.x;     // 0..127
  const int tp  = tid >> 6;        // 0..1
  const int np  = tid & 63;        // n-pair index
  const int t   = blockIdx.x * 2 + tp;
  const int n0  = np * 2;

  const float2 sub2 = *reinterpret_cast<const float2*>(wsLZ + n0);
  const unsigned short* yr = wsYT + (size_t)t * (40 * 128) + n0;
  float* r0 = &L[(tp * 128 + n0) * 47];
  float* r1 = r0 + 47;
#pragma unroll
  for (int c = 0; c < 40; ++c) {
    uint32_t v = *reinterpret_cast<const uint32_t*>(yr + c * 128);
    r0[c] = bf2f((unsigned short)(v & 0xFFFF)) - sub2.x;
    r1[c] = bf2f((unsigned short)(v >> 16)) - sub2.y;
  }

  const float* mp = wsMod + (size_t)t * (3 * 128) + n0;
  const float2 y40 = *reinterpret_cast<const float2*>(mp);
  const float2 y41 = *reinterpret_cast<const float2*>(mp + 128);
  const float2 y42 = *reinterpret_cast<const float2*>(mp + 256);

#define MODROW(R, A, B, C)  do {                                             \
    const float m01 = fmaxf(A, B);                                           \
    const float l01 = m01 + log1pf(__expf(fminf(A, B) - m01));               \
    const float m02 = fmaxf(A, C);                                           \
    const float l02 = m02 + log1pf(__expf(fminf(A, C) - m02));               \
    R[40] = A - l01; R[41] = B - l01;                                        \
    R[42] = A - l02; R[43] = C - l02;                                        \
    R[44] = 0.f;     R[45] = 0.f;                                            \
  } while (0)
  MODROW(r0, y40.x, y41.x, y42.x);
  MODROW(r1, y40.y, y41.y, y42.y);
#undef MODROW
  __syncthreads();

  const size_t base = (size_t)blockIdx.x * (256 * 46);
#pragma unroll
  for (int j = 0; j < 92; ++j) {
    const int e = j * 128 + tid;
    const int r = e / 46;           // const-divisor -> magic-mul
    const int c = e - r * 46;
    __builtin_nontemporal_store(L[r * 47 + c], &out[base + e]);
  }
}

extern "C" void kernel_launch(void* const* d_in, const int* in_sizes, int n_in,
                              void* d_out, int out_size, void* d_ws, size_t ws_size,
                              hipStream_t stream) {
  (void)in_sizes; (void)n_in; (void)out_size; (void)ws_size;
  const float* x = (const float*)d_in[0];
  const float* W = (const float*)d_in[1];
  const float* b = (const float*)d_in[2];
  float* out = (float*)d_out;

  char* wsb = (char*)d_ws;
  unsigned short* wsYT = (unsigned short*)wsb;               // 2000*40*128 bf16
  float* wsMod   = (float*)(wsb + (size_t)T_DIM * 40 * 128 * 2);   // 2000*3*128 f32
  float* wsM     = wsMod + (size_t)T_DIM * 3 * N_DIM;        // 250*128*64
  float* wsScale = wsM + (size_t)NCHUNK * N_DIM * 64;        // 250*128
  float* wsM2    = wsScale + NCHUNK * N_DIM;                 // 25*128*64
  float* wsScale2= wsM2 + (size_t)NSUPER * N_DIM * 64;       // 25*128
  float* wsLZ    = wsScale2 + NSUPER * N_DIM;                // 128

  hipLaunchKernelGGL(k1_fused,  dim3(NCHUNK), dim3(1024), 0, stream,
                     x, W, b, wsYT, wsMod, wsM, wsScale);
  hipLaunchKernelGGL(k2c_super, dim3(NSUPER), dim3(128), 0, stream,
                     wsM, wsScale, wsM2, wsScale2);
  hipLaunchKernelGGL(k2b_fold,  dim3(8), dim3(128), 0, stream,
                     wsM2, wsScale2, wsLZ);
  hipLaunchKernelGGL(k3_out,    dim3(NROWS / 256), dim3(128), 0, stream,
                     wsYT, wsMod, wsLZ, out);
}

// Round 12
// 100.021 us; speedup vs baseline: 1.3165x; 1.3165x over previous
//
#include <hip/hip_runtime.h>

#define T_DIM 2000
#define N_DIM 128
#define IN_DIM 256
#define OUT_C 46
#define NROWS (T_DIM * N_DIM)
#define NCHUNK 250
#define CLEN 8
#define NSUPER 25
#define SLEN 10

typedef short bf16x8 __attribute__((ext_vector_type(8)));
typedef float f32x4 __attribute__((ext_vector_type(4)));

union F8U { bf16x8 v; uint32_t u[4]; };

__device__ __forceinline__ uint32_t cvtpk(float lo, float hi) {
  uint32_t r;
  asm("v_cvt_pk_bf16_f32 %0, %1, %2" : "=v"(r) : "v"(lo), "v"(hi));
  return r;
}

__device__ __forceinline__ float bf2f(unsigned short u) {
  uint32_t w = (uint32_t)u << 16;
  return __builtin_bit_cast(float, w);
}

#define LDSK 264  // padded W row length (shorts)
#define YPAD 132  // padded Yst row length (shorts): 33 uint2, stride breaks banks

// ---------------------------------------------------------------------------
// k1: y = x @ W^T + b via MFMA 16x16x32 bf16 (W in LDS bf16, half-tile
// ping-pong A prefetch, plain cached x loads).  Trans scores are staged in a
// padded LDS block Yst[2t][40c][128n] and flushed with fully-coalesced uint2
// runs (the old direct uint2 stores were a 32B-granule scatter, 2x write
// transactions).  Mods y40..42 go fp32 to wsMod.  LDS 44KB -> 3 blocks/CU.
// ---------------------------------------------------------------------------
__global__ __launch_bounds__(256, 3) void k1_gemm(const float* __restrict__ x,
                                                  const float* __restrict__ W,
                                                  const float* __restrict__ b,
                                                  unsigned short* __restrict__ wsYT,
                                                  float* __restrict__ wsMod) {
  __shared__ unsigned short Wl[43 * LDSK];    // 22.7 KB
  __shared__ unsigned short Yst[2 * 40 * YPAD]; // 21.1 KB
  const int tid  = threadIdx.x;
  const int lane = tid & 63;
  const int wv   = tid >> 6;
  const int ln   = lane & 15;   // A-row(n) / B-col(c) index
  const int lh   = lane >> 4;   // k-group

  {  // stage W as bf16 into padded LDS rows
    uint32_t* Wd = reinterpret_cast<uint32_t*>(Wl);
#pragma unroll
    for (int it = 0; it < 22; ++it) {
      int e = tid + it * 256;
      if (e < 43 * 128) {
        int n = e >> 7, kp = e & 127;
        float2 w = *reinterpret_cast<const float2*>(W + (size_t)n * IN_DIM + 2 * kp);
        Wd[n * (LDSK / 2) + kp] = cvtpk(w.x, w.y);
      }
    }
  }
  float bias[3];
#pragma unroll
  for (int nt = 0; nt < 3; ++nt) {
    int n = nt * 16 + ln;
    bias[nt] = b[n > 42 ? 42 : n];
  }
  __syncthreads();

  const int rowbase = blockIdx.x * 256 + wv * 64;
  const float* xbase = x + (size_t)(rowbase + ln) * IN_DIM + lh * 8;

  f32x4 bufA[8], bufB[8];
  f32x4 zero = {0.f, 0.f, 0.f, 0.f};
  f32x4 acc[3] = {zero, zero, zero};

#define LOADH(BUF, T, HF) do {                                               \
    const float* _p = xbase + (size_t)(T) * (16 * IN_DIM) + (HF) * 128;      \
    _Pragma("unroll")                                                        \
    for (int _s = 0; _s < 4; ++_s) {                                         \
      BUF[_s]     = *reinterpret_cast<const f32x4*>(_p + _s * 32);           \
      BUF[_s + 4] = *reinterpret_cast<const f32x4*>(_p + _s * 32 + 4);       \
    }                                                                        \
  } while (0)

#define COMPH(BUF, HF) do {                                                  \
    _Pragma("unroll")                                                        \
    for (int _s2 = 0; _s2 < 4; ++_s2) {                                      \
      F8U _af;                                                               \
      _af.u[0] = cvtpk(BUF[_s2].x, BUF[_s2].y);                              \
      _af.u[1] = cvtpk(BUF[_s2].z, BUF[_s2].w);                              \
      _af.u[2] = cvtpk(BUF[_s2 + 4].x, BUF[_s2 + 4].y);                      \
      _af.u[3] = cvtpk(BUF[_s2 + 4].z, BUF[_s2 + 4].w);                      \
      const int _s = (HF) * 4 + _s2;                                         \
      _Pragma("unroll")                                                      \
      for (int _nt = 0; _nt < 3; ++_nt) {                                    \
        const bf16x8 _bf = *reinterpret_cast<const bf16x8*>(                 \
            &Wl[(_nt * 16 + ln) * LDSK + _s * 32 + lh * 8]);                 \
        acc[_nt] = __builtin_amdgcn_mfma_f32_16x16x32_bf16(_af.v, _bf,       \
                                                           acc[_nt], 0, 0, 0);\
      }                                                                      \
    }                                                                        \
  } while (0)

  LOADH(bufA, 0, 0);
  LOADH(bufB, 0, 1);
#pragma unroll 1
  for (int t = 0; t < 4; ++t) {
    COMPH(bufA, 0);
    if (t < 3) LOADH(bufA, t + 1, 0);
    COMPH(bufB, 1);
    if (t < 3) LOADH(bufB, t + 1, 1);
    const int R0   = rowbase + t * 16;
    const int tloc = (R0 >> 7) & 1;            // 0..1 within block
    const int n0   = (R0 & 127) + lh * 4;      // 4 consecutive n
#pragma unroll
    for (int nt = 0; nt < 3; ++nt) {
      const int c = nt * 16 + ln;
      if (nt < 2 || ln < 8) {        // trans scores c<40 -> LDS Yst
        uint32_t d0 = cvtpk(acc[nt][0] + bias[nt], acc[nt][1] + bias[nt]);
        uint32_t d1 = cvtpk(acc[nt][2] + bias[nt], acc[nt][3] + bias[nt]);
        uint2 v; v.x = d0; v.y = d1;
        *reinterpret_cast<uint2*>(&Yst[(tloc * 40 + c) * YPAD + n0]) = v;
      } else if (ln < 11) {          // c = 40..42 -> fp32 wsMod[t][c-40][n]
        const int tt = R0 >> 7;
        float4 v;
        v.x = acc[2][0] + bias[2]; v.y = acc[2][1] + bias[2];
        v.z = acc[2][2] + bias[2]; v.w = acc[2][3] + bias[2];
        *reinterpret_cast<float4*>(
            wsMod + ((size_t)tt * 3 + (ln - 8)) * 128 + n0) = v;
      }
      acc[nt] = zero;
    }
  }
#undef LOADH
#undef COMPH

  __syncthreads();
  // flush Yst -> wsYT: 2560 uint2, fully coalesced (8B/lane, 2KB/wave-instr)
  uint2* gp = reinterpret_cast<uint2*>(wsYT + (size_t)blockIdx.x * (2 * 40 * 128));
  const uint2* lp = reinterpret_cast<const uint2*>(Yst);
#pragma unroll
  for (int it = 0; it < 10; ++it) {
    const int e   = tid + it * 256;   // 0..2559
    const int row = e >> 5;           // 2t*40c = 80 rows of 32 uint2
    const int q   = e & 31;
    gp[e] = lp[row * 33 + q];         // YPAD shorts = 33 uint2
  }
}

// ---------------------------------------------------------------------------
// k2a: per (chunk c, column n), one lane builds the 8x8 linear-space product
// of CLEN=8 step matrices.  250 blocks x 128 threads: c = blockIdx, n = tid
// -> full 256B wsYT rows per block, spread over ~250 CUs.
// ---------------------------------------------------------------------------
__global__ __launch_bounds__(128, 1) void k2a_chunk(const unsigned short* __restrict__ wsYT,
                                                    float* __restrict__ wsM,
                                                    float* __restrict__ wsScale) {
  const int c  = blockIdx.x;
  const int n  = threadIdx.x;
  const int t0 = c * CLEN;

  float M[8][8];
  float lsc = 0.f;
  float bufA[40], bufB[40];

#define LOADROW(BUF, TROW) do {                                              \
    const unsigned short* _yr = wsYT + (size_t)(TROW) * (40 * 128) + n;      \
    _Pragma("unroll")                                                        \
    for (int _q = 0; _q < 40; ++_q) BUF[_q] = bf2f(_yr[_q * 128]);           \
  } while (0)

#define INITM(BUF) do {                                                      \
    float _e[40];                                                            \
    _Pragma("unroll")                                                        \
    for (int _q = 0; _q < 40; ++_q) _e[_q] = __expf(BUF[_q]);                \
    _Pragma("unroll")                                                        \
    for (int _i = 0; _i < 4; ++_i)                                           \
      _Pragma("unroll")                                                      \
      for (int _j = 0; _j < 8; ++_j) M[_i][_j] = _e[8*_i+_j];                \
    _Pragma("unroll")                                                        \
    for (int _d = 0; _d < 4; ++_d) {                                         \
      _Pragma("unroll")                                                      \
      for (int _j = 0; _j < 8; ++_j) M[4+_d][_j] = 0.f;                      \
      M[4+_d][_d]   = _e[32+_d];                                             \
      M[4+_d][4+_d] = _e[36+_d];                                             \
    }                                                                        \
  } while (0)

#define STEPM(BUF) do {                                                      \
    float _e[40];                                                            \
    _Pragma("unroll")                                                        \
    for (int _q = 0; _q < 40; ++_q) _e[_q] = __expf(BUF[_q]);                \
    float _nm[8][8];                                                         \
    _Pragma("unroll")                                                        \
    for (int _j = 0; _j < 8; ++_j) {                                         \
      _Pragma("unroll")                                                      \
      for (int _i = 0; _i < 4; ++_i) {                                       \
        float _a = _e[8*_i+0]*M[0][_j] + _e[8*_i+1]*M[1][_j];                \
        float _b = _e[8*_i+2]*M[2][_j] + _e[8*_i+3]*M[3][_j];                \
        float _c = _e[8*_i+4]*M[4][_j] + _e[8*_i+5]*M[5][_j];                \
        float _d = _e[8*_i+6]*M[6][_j] + _e[8*_i+7]*M[7][_j];                \
        _nm[_i][_j] = (_a + _b) + (_c + _d);                                 \
      }                                                                      \
      _Pragma("unroll")                                                      \
      for (int _d2 = 0; _d2 < 4; ++_d2)                                      \
        _nm[4+_d2][_j] = _e[32+_d2]*M[_d2][_j] + _e[36+_d2]*M[4+_d2][_j];    \
    }                                                                        \
    _Pragma("unroll")                                                        \
    for (int _i = 0; _i < 8; ++_i)                                           \
      _Pragma("unroll")                                                      \
      for (int _j = 0; _j < 8; ++_j) M[_i][_j] = _nm[_i][_j];                \
  } while (0)

#define RENORM do {                                                          \
    float _S = 0.f;                                                          \
    _Pragma("unroll")                                                        \
    for (int _i = 0; _i < 8; ++_i)                                           \
      _Pragma("unroll")                                                      \
      for (int _j = 0; _j < 8; ++_j) _S += M[_i][_j];                        \
    lsc += __logf(_S);                                                       \
    const float _inv = 1.0f / _S;                                            \
    _Pragma("unroll")                                                        \
    for (int _i = 0; _i < 8; ++_i)                                           \
      _Pragma("unroll")                                                      \
      for (int _j = 0; _j < 8; ++_j) M[_i][_j] *= _inv;                      \
  } while (0)

  LOADROW(bufA, t0);
  LOADROW(bufB, t0 + 1);
  INITM(bufA);               // row 0
  LOADROW(bufA, t0 + 2);
  STEPM(bufB);               // row 1
  LOADROW(bufB, t0 + 3);
  STEPM(bufA);               // row 2
  LOADROW(bufA, t0 + 4);
  STEPM(bufB);               // row 3
  RENORM;
  LOADROW(bufB, t0 + 5);
  STEPM(bufA);               // row 4
  LOADROW(bufA, t0 + 6);
  STEPM(bufB);               // row 5
  LOADROW(bufB, t0 + 7);
  STEPM(bufA);               // row 6
  STEPM(bufB);               // row 7
  RENORM;

#undef LOADROW
#undef INITM
#undef STEPM
#undef RENORM

  float* dst = wsM + (size_t)(c * N_DIM + n) * 64;
#pragma unroll
  for (int q = 0; q < 16; ++q) {
    float4 v;
    v.x = M[q >> 1][(q & 1) * 4 + 0];
    v.y = M[q >> 1][(q & 1) * 4 + 1];
    v.z = M[q >> 1][(q & 1) * 4 + 2];
    v.w = M[q >> 1][(q & 1) * 4 + 3];
    reinterpret_cast<float4*>(dst)[q] = v;
  }
  wsScale[c * N_DIM + n] = lsc;
}

// ---------------------------------------------------------------------------
// k2c: fold SLEN=10 chunk matrices into one super-matrix, ping-pong prefetch.
// ---------------------------------------------------------------------------
__global__ __launch_bounds__(128, 1) void k2c_super(const float* __restrict__ wsM,
                                                    const float* __restrict__ wsScale,
                                                    float* __restrict__ wsM2,
                                                    float* __restrict__ wsScale2) {
  const int sI = blockIdx.x;     // 0..24
  const int n  = threadIdx.x;    // 0..127
  const int c0 = sI * SLEN;

  float A[8][8], B0[8][8], B1[8][8];
  float lsc = 0.f;
#pragma unroll
  for (int u = 0; u < SLEN; ++u) lsc += wsScale[(c0 + u) * N_DIM + n];

#define LOADM(DST, CIDX) do {                                                \
    const float4* _p = reinterpret_cast<const float4*>(                      \
        wsM + (size_t)((CIDX) * N_DIM + n) * 64);                            \
    _Pragma("unroll")                                                        \
    for (int _q = 0; _q < 16; ++_q) {                                        \
      float4 _v = _p[_q];                                                    \
      DST[_q >> 1][(_q & 1) * 4 + 0] = _v.x;                                 \
      DST[_q >> 1][(_q & 1) * 4 + 1] = _v.y;                                 \
      DST[_q >> 1][(_q & 1) * 4 + 2] = _v.z;                                 \
      DST[_q >> 1][(_q & 1) * 4 + 3] = _v.w;                                 \
    }                                                                        \
  } while (0)

#define FOLD(BB) do {                                                        \
    float C[8][8];                                                           \
    _Pragma("unroll")                                                        \
    for (int _i = 0; _i < 8; ++_i)                                           \
      _Pragma("unroll")                                                      \
      for (int _j = 0; _j < 8; ++_j) {                                       \
        float _a = BB[_i][0]*A[0][_j] + BB[_i][1]*A[1][_j];                  \
        float _b = BB[_i][2]*A[2][_j] + BB[_i][3]*A[3][_j];                  \
        float _c = BB[_i][4]*A[4][_j] + BB[_i][5]*A[5][_j];                  \
        float _d = BB[_i][6]*A[6][_j] + BB[_i][7]*A[7][_j];                  \
        C[_i][_j] = (_a + _b) + (_c + _d);                                   \
      }                                                                      \
    float _S = 0.f;                                                          \
    _Pragma("unroll")                                                        \
    for (int _i = 0; _i < 8; ++_i)                                           \
      _Pragma("unroll")                                                      \
      for (int _j = 0; _j < 8; ++_j) _S += C[_i][_j];                        \
    lsc += __logf(_S);                                                       \
    const float _inv = 1.0f / _S;                                            \
    _Pragma("unroll")                                                        \
    for (int _i = 0; _i < 8; ++_i)                                           \
      _Pragma("unroll")                                                      \
      for (int _j = 0; _j < 8; ++_j) A[_i][_j] = C[_i][_j] * _inv;           \
  } while (0)

  LOADM(A, c0);
  LOADM(B0, c0 + 1);
  LOADM(B1, c0 + 2);
  FOLD(B0); LOADM(B0, c0 + 3);
  FOLD(B1); LOADM(B1, c0 + 4);
  FOLD(B0); LOADM(B0, c0 + 5);
  FOLD(B1); LOADM(B1, c0 + 6);
  FOLD(B0); LOADM(B0, c0 + 7);
  FOLD(B1); LOADM(B1, c0 + 8);
  FOLD(B0); LOADM(B0, c0 + 9);
  FOLD(B1);
  FOLD(B0);
#undef LOADM
#undef FOLD

  float* dst = wsM2 + (size_t)(sI * N_DIM + n) * 64;
#pragma unroll
  for (int q = 0; q < 16; ++q) {
    float4 v;
    v.x = A[q >> 1][(q & 1) * 4 + 0];
    v.y = A[q >> 1][(q & 1) * 4 + 1];
    v.z = A[q >> 1][(q & 1) * 4 + 2];
    v.w = A[q >> 1][(q & 1) * 4 + 3];
    reinterpret_cast<float4*>(dst)[q] = v;
  }
  wsScale2[sI * N_DIM + n] = lsc;
}

// ---------------------------------------------------------------------------
// k2b: fold p0 through the 25 super-matrices. 8 lanes per column n.
// ---------------------------------------------------------------------------
__global__ __launch_bounds__(128, 1) void k2b_fold(const float* __restrict__ wsM2,
                                                   const float* __restrict__ wsScale2,
                                                   float* __restrict__ wsLZ) {
  const int tid = threadIdx.x;
  const int n = blockIdx.x * 16 + (tid >> 3);
  const int i = tid & 7;
  const int gbase = (tid & 63) & ~7;

  float4 r0[NSUPER], r1[NSUPER];
  float sc[NSUPER];
#pragma unroll
  for (int s = 0; s < NSUPER; ++s) {
    const float* Mp = wsM2 + ((size_t)(s * N_DIM + n) * 64 + i * 8);
    r0[s] = *reinterpret_cast<const float4*>(Mp);
    r1[s] = *reinterpret_cast<const float4*>(Mp + 4);
    sc[s] = wsScale2[s * N_DIM + n];
  }

  float p[8] = {1.f, 1.f, 1.f, 1.f, 0.f, 0.f, 0.f, 0.f};
  float lz = 0.f;
#pragma unroll
  for (int s = 0; s < NSUPER; ++s) {
    float np = r0[s].x * p[0] + r0[s].y * p[1] + r0[s].z * p[2] + r0[s].w * p[3]
             + r1[s].x * p[4] + r1[s].y * p[5] + r1[s].z * p[6] + r1[s].w * p[7];
#pragma unroll
    for (int j = 0; j < 8; ++j) p[j] = __shfl(np, gbase + j, 64);
    float S = ((p[0] + p[1]) + (p[2] + p[3])) + ((p[4] + p[5]) + (p[6] + p[7]));
    lz += __logf(S) + sc[s];
    const float inv = 1.0f / S;
#pragma unroll
    for (int j = 0; j < 8; ++j) p[j] *= inv;
  }
  if (i == 0) wsLZ[n] = lz * (1.0f / (float)T_DIM);
}

// ---------------------------------------------------------------------------
// k3: write the WHOLE output.  Block = 256 rows (2 t x 128 n); each thread
// builds its row in padded LDS, then a flat coalesced copy with NONTEMPORAL
// stores (out is write-once; keep wsYT/x resident in L2/L3).
// ---------------------------------------------------------------------------
__global__ __launch_bounds__(256, 3) void k3_out(const unsigned short* __restrict__ wsYT,
                                                 const float* __restrict__ wsMod,
                                                 const float* __restrict__ wsLZ,
                                                 float* __restrict__ out) {
  __shared__ float L[256 * 47];
  const int tid = threadIdx.x;
  const int fr  = blockIdx.x * 256 + tid;
  const int t   = fr >> 7;
  const int n   = fr & 127;
  const float sub = wsLZ[n];

  const unsigned short* yr = wsYT + (size_t)t * (40 * 128) + n;
  float* lrow = &L[tid * 47];
#pragma unroll
  for (int c = 0; c < 40; ++c) lrow[c] = bf2f(yr[c * 128]) - sub;

  const float* mp = wsMod + (size_t)t * (3 * 128) + n;
  const float y40 = mp[0], y41 = mp[128], y42 = mp[256];
  const float m01 = fmaxf(y40, y41);
  const float l01 = m01 + log1pf(__expf(fminf(y40, y41) - m01));
  const float m02 = fmaxf(y40, y42);
  const float l02 = m02 + log1pf(__expf(fminf(y40, y42) - m02));
  lrow[40] = y40 - l01;
  lrow[41] = y41 - l01;
  lrow[42] = y40 - l02;
  lrow[43] = y42 - l02;
  lrow[44] = 0.f;
  lrow[45] = 0.f;
  __syncthreads();

  const size_t base = (size_t)blockIdx.x * (256 * 46);
#pragma unroll
  for (int j = 0; j < 46; ++j) {
    const int e = j * 256 + tid;
    const int r = e / 46;           // const-divisor -> magic-mul
    const int c = e - r * 46;
    __builtin_nontemporal_store(L[r * 47 + c], &out[base + e]);
  }
}

extern "C" void kernel_launch(void* const* d_in, const int* in_sizes, int n_in,
                              void* d_out, int out_size, void* d_ws, size_t ws_size,
                              hipStream_t stream) {
  (void)in_sizes; (void)n_in; (void)out_size; (void)ws_size;
  const float* x = (const float*)d_in[0];
  const float* W = (const float*)d_in[1];
  const float* b = (const float*)d_in[2];
  float* out = (float*)d_out;

  char* wsb = (char*)d_ws;
  unsigned short* wsYT = (unsigned short*)wsb;               // 2000*40*128 bf16
  float* wsMod   = (float*)(wsb + (size_t)T_DIM * 40 * 128 * 2);   // 2000*3*128 f32
  float* wsM     = wsMod + (size_t)T_DIM * 3 * N_DIM;        // 250*128*64
  float* wsScale = wsM + (size_t)NCHUNK * N_DIM * 64;        // 250*128
  float* wsM2    = wsScale + NCHUNK * N_DIM;                 // 25*128*64
  float* wsScale2= wsM2 + (size_t)NSUPER * N_DIM * 64;       // 25*128
  float* wsLZ    = wsScale2 + NSUPER * N_DIM;                // 128

  hipLaunchKernelGGL(k1_gemm,   dim3(NROWS / 256), dim3(256), 0, stream,
                     x, W, b, wsYT, wsMod);
  hipLaunchKernelGGL(k2a_chunk, dim3(NCHUNK), dim3(128), 0, stream,
                     wsYT, wsM, wsScale);
  hipLaunchKernelGGL(k2c_super, dim3(NSUPER), dim3(128), 0, stream,
                     wsM, wsScale, wsM2, wsScale2);
  hipLaunchKernelGGL(k2b_fold,  dim3(8), dim3(128), 0, stream,
                     wsM2, wsScale2, wsLZ);
  hipLaunchKernelGGL(k3_out,    dim3(NROWS / 256), dim3(256), 0, stream,
                     wsYT, wsMod, wsLZ, out);
}